// Round 8
// baseline (348.418 us; speedup 1.0000x reference)
//
#include <hip/hip_runtime.h>

#define D 256
#define KDIM 512
#define BCAP 16384  // per-bucket staging capacity (avg fill 8192 for E=3.2M, B1=391)
#define EPB 8192    // edges per scatter block
#define BM 64       // rows per fused block

typedef __bf16 bf16_t;
typedef bf16_t bf16x8 __attribute__((ext_vector_type(8)));
typedef bf16_t bf16x4 __attribute__((ext_vector_type(4)));
typedef float f32x4_t __attribute__((ext_vector_type(4)));
typedef float f32x2_t __attribute__((ext_vector_type(2)));

// async global->LDS, 16B/lane; LDS dest is wave-uniform base + lane*16
__device__ __forceinline__ void async_cp16(const void* g, void* l) {
    __builtin_amdgcn_global_load_lds(
        (const __attribute__((address_space(1))) unsigned int*)g,
        (__attribute__((address_space(3))) unsigned int*)l, 16, 0, 0);
}

// ---------------- CSR build (bucketed, block-aggregated scatter) -----------

__global__ __launch_bounds__(256) void k_scatter1(const int* __restrict__ eidx,
                                                  int* __restrict__ bcur,
                                                  int* __restrict__ staging, int E) {
    __shared__ int lhist[512];
    __shared__ int lcur[512];
    __shared__ int gbase[512];
    const int t = threadIdx.x;
    const int e0 = blockIdx.x * EPB;
    int e1 = e0 + EPB;
    if (e1 > E) e1 = E;

    lhist[t] = 0;
    lhist[t + 256] = 0;
    lcur[t] = 0;
    lcur[t + 256] = 0;
    __syncthreads();

    for (int e = e0 + t; e < e1; e += 256) {
        int d = eidx[E + e];
        atomicAdd(&lhist[d >> 8], 1);
    }
    __syncthreads();

#pragma unroll
    for (int b = t; b < 512; b += 256) {
        int c = lhist[b];
        gbase[b] = (c > 0) ? atomicAdd(&bcur[b * 16], c) : 0;
    }
    __syncthreads();

    for (int e = e0 + t; e < e1; e += 256) {
        int s = eidx[e];
        int d = eidx[E + e];
        int b = d >> 8;
        int pos = gbase[b] + atomicAdd(&lcur[b], 1);
        staging[(size_t)b * BCAP + pos] = ((d & 255) << 24) | s;  // s < 2^24
    }
}

__global__ __launch_bounds__(512) void k_bbase(const int* __restrict__ bcur,
                                               int* __restrict__ bbase,
                                               int* __restrict__ row_ptr,
                                               int B1, int N, int E) {
    __shared__ int sm[512];
    int t = threadIdx.x;
    int v = (t < B1) ? bcur[t * 16] : 0;
    sm[t] = v;
    __syncthreads();
    for (int off = 1; off < 512; off <<= 1) {
        int u = (t >= off) ? sm[t - off] : 0;
        __syncthreads();
        sm[t] += u;
        __syncthreads();
    }
    if (t < B1) bbase[t] = sm[t] - v;  // exclusive
    if (t == 0) row_ptr[N] = E;
}

__global__ __launch_bounds__(256) void k_bucket(const int* __restrict__ bcur,
                                                const int* __restrict__ bbase,
                                                const int* __restrict__ staging,
                                                int* __restrict__ edge_src,
                                                int* __restrict__ row_ptr, int N) {
    __shared__ int lhist[256];
    __shared__ int lscan[256];
    __shared__ int lcur[256];
    int b = blockIdx.x, t = threadIdx.x;
    int node_base = b << 8;
    int nn = N - node_base;
    if (nn > 256) nn = 256;
    int cnt = bcur[b * 16];
    int base = bbase[b];
    const int* stg = staging + (size_t)b * BCAP;

    lhist[t] = 0;
    __syncthreads();
    for (int i = t; i < cnt; i += 256)
        atomicAdd(&lhist[((unsigned)stg[i]) >> 24], 1);
    __syncthreads();
    int v = lhist[t];
    lscan[t] = v;
    __syncthreads();
    for (int off = 1; off < 256; off <<= 1) {
        int u = (t >= off) ? lscan[t - off] : 0;
        __syncthreads();
        lscan[t] += u;
        __syncthreads();
    }
    int excl = lscan[t] - v;
    if (t < nn) row_ptr[node_base + t] = base + excl;
    lscan[t] = excl;
    lcur[t] = 0;
    __syncthreads();
    for (int i = t; i < cnt; i += 256) {
        int w = stg[i];
        int ln = ((unsigned)w) >> 24;
        int src = w & 0xFFFFFF;
        int pos = base + lscan[ln] + atomicAdd(&lcur[ln], 1);
        edge_src[pos] = src;
    }
}

// ---------------- conversions ----------------

// x (f32) -> Xq (fp8 e4m3, linear gather table) AND Xb (bf16, PRE-SWIZZLED:
// 16B-block blk of row r stored at blk ^ ((r&7)<<2), matching A_lds layout)
__global__ __launch_bounds__(256) void k_convx(const float* __restrict__ x,
                                               unsigned int* __restrict__ Xq,
                                               bf16_t* __restrict__ Xb,
                                               int total8) {
    int i = blockIdx.x * 256 + threadIdx.x;  // one thread = 8 elems = one 16B blk
    if (i >= total8) return;
    float4 v0 = *(const float4*)(x + (size_t)i * 8);
    float4 v1 = *(const float4*)(x + (size_t)i * 8 + 4);
    int w0 = 0, w1 = 0;
    w0 = __builtin_amdgcn_cvt_pk_fp8_f32(v0.x, v0.y, w0, false);
    w0 = __builtin_amdgcn_cvt_pk_fp8_f32(v0.z, v0.w, w0, true);
    w1 = __builtin_amdgcn_cvt_pk_fp8_f32(v1.x, v1.y, w1, false);
    w1 = __builtin_amdgcn_cvt_pk_fp8_f32(v1.z, v1.w, w1, true);
    uint2 o = {(unsigned)w0, (unsigned)w1};
    *(uint2*)(Xq + (size_t)i * 2) = o;
    bf16x8 ob = {(bf16_t)v0.x, (bf16_t)v0.y, (bf16_t)v0.z, (bf16_t)v0.w,
                 (bf16_t)v1.x, (bf16_t)v1.y, (bf16_t)v1.z, (bf16_t)v1.w};
    int row = i >> 5;
    int blk = i & 31;
    int dblk = blk ^ ((row & 7) << 2);
    *(bf16x8*)(Xb + (size_t)row * D + dblk * 8) = ob;
}

// Wcat [256][512] bf16: [:,0:256]=W_l, [:,256:512]=W_r
__global__ __launch_bounds__(256) void k_convw(const float* __restrict__ Wl,
                                               const float* __restrict__ Wr,
                                               bf16_t* __restrict__ Wcat) {
    int i = blockIdx.x * 256 + threadIdx.x;
    if (i >= D * KDIM / 4) return;
    int o = i * 4;
    int j = o >> 9;
    int k = o & 511;
    const float* src = (k < D) ? (Wl + (size_t)j * D + k)
                               : (Wr + (size_t)j * D + (k - D));
    float4 v = *(const float4*)src;
    bf16x4 ov = {(bf16_t)v.x, (bf16_t)v.y, (bf16_t)v.z, (bf16_t)v.w};
    *(bf16x4*)(Wcat + o) = ov;
}

// ------- FUSED: gather-mean -> LDS A-panel -> GEMM (barrier-free k-loop)
//         -> A-panel reload with bf16(x) -> GEMM half 2 -> GELU+LN+residual.
// 256 thr = 4 waves; block tile 64 rows x 256 cols; wave = 64 rows x 64 cols.
// A_lds[64][256] bf16, 16B-blocks XOR-swizzled by ((row&7)<<2).
// B (Wcat) is 256KB, L2-resident: loaded direct-to-register each k-step.

__global__ __launch_bounds__(256, 4) void k_fused(
        const int* __restrict__ row_ptr, const int* __restrict__ edge_src,
        const unsigned int* __restrict__ Xq, const bf16_t* __restrict__ Xb,
        const bf16_t* __restrict__ Wcat, const float* __restrict__ b_l,
        const float* __restrict__ gamma, const float* __restrict__ beta,
        float* __restrict__ out, int M) {
    __shared__ __align__(16) bf16_t A_lds[BM * D];  // 32 KB
    __shared__ float sm_s[4][BM];
    __shared__ float sm_q[4][BM];

    const int tid = threadIdx.x;
    const int lane = tid & 63;
    const int wid = tid >> 6;   // wave 0..3 -> 64-col strip
    const int lr = lane & 15;
    const int lh = lane >> 4;
    const int g = lane >> 4;    // gather: neighbor subgroup
    const int c16 = lane & 15;  // gather: 16-fp8 column chunk
    const int row0 = blockIdx.x * BM;

    // ---- phase 1: gather-mean 16 rows per wave into swizzled A_lds ----
    for (int rr = 0; rr < 16; ++rr) {
        int rl = wid * 16 + rr;
        int node = row0 + rl;
        if (node > M - 1) node = M - 1;
        int beg = row_ptr[node];
        int end = row_ptr[node + 1];

        float acc[16];
#pragma unroll
        for (int k = 0; k < 16; k++) acc[k] = 0.f;

#define ACC4(w, bidx)                                            \
    {                                                            \
        f32x2_t lo = __builtin_amdgcn_cvt_pk_f32_fp8((w), false);\
        f32x2_t hi = __builtin_amdgcn_cvt_pk_f32_fp8((w), true); \
        acc[(bidx) + 0] += lo[0];                                \
        acc[(bidx) + 1] += lo[1];                                \
        acc[(bidx) + 2] += hi[0];                                \
        acc[(bidx) + 3] += hi[1];                                \
    }
        for (int j = beg; j < end; j += 8) {
            int j0 = j + g, j1 = j + 4 + g;
            bool ok0 = j0 < end, ok1 = j1 < end;
            int s0 = edge_src[ok0 ? j0 : beg];
            int s1 = edge_src[ok1 ? j1 : beg];
            uint4 v0 = *(const uint4*)(Xq + (size_t)s0 * 64 + c16 * 4);
            uint4 v1 = *(const uint4*)(Xq + (size_t)s1 * 64 + c16 * 4);
            if (!ok0) { v0.x = 0; v0.y = 0; v0.z = 0; v0.w = 0; }
            if (!ok1) { v1.x = 0; v1.y = 0; v1.z = 0; v1.w = 0; }
            ACC4(v0.x, 0) ACC4(v0.y, 4) ACC4(v0.z, 8) ACC4(v0.w, 12)
            ACC4(v1.x, 0) ACC4(v1.y, 4) ACC4(v1.z, 8) ACC4(v1.w, 12)
        }
#undef ACC4

#pragma unroll
        for (int k = 0; k < 16; k++) {
            acc[k] += __shfl_xor(acc[k], 16, 64);
            acc[k] += __shfl_xor(acc[k], 32, 64);
        }
        int dg = end - beg;
        float inv = 1.0f / (float)(dg > 0 ? dg : 1);
        if (g == 0) {  // lanes 0..15: cols c16*16 .. c16*16+15
            int f = (rl & 7) << 2;
            bf16x8 o0 = {(bf16_t)(acc[0] * inv), (bf16_t)(acc[1] * inv),
                         (bf16_t)(acc[2] * inv), (bf16_t)(acc[3] * inv),
                         (bf16_t)(acc[4] * inv), (bf16_t)(acc[5] * inv),
                         (bf16_t)(acc[6] * inv), (bf16_t)(acc[7] * inv)};
            bf16x8 o1 = {(bf16_t)(acc[8] * inv), (bf16_t)(acc[9] * inv),
                         (bf16_t)(acc[10] * inv), (bf16_t)(acc[11] * inv),
                         (bf16_t)(acc[12] * inv), (bf16_t)(acc[13] * inv),
                         (bf16_t)(acc[14] * inv), (bf16_t)(acc[15] * inv)};
            *(bf16x8*)&A_lds[rl * D + ((2 * c16) ^ f) * 8] = o0;
            *(bf16x8*)&A_lds[rl * D + ((2 * c16 + 1) ^ f) * 8] = o1;
        }
    }
    __syncthreads();

    // ---- phase 2: GEMM, K half 1 (agg x W_l). Barrier-free. ----
    f32x4_t acc[4][4];
#pragma unroll
    for (int i = 0; i < 4; i++)
#pragma unroll
        for (int j = 0; j < 4; j++) acc[i][j] = (f32x4_t){0.f, 0.f, 0.f, 0.f};

    const bf16_t* wb = Wcat + (size_t)(wid * 64 + lr) * KDIM;

#define KHALF(koff)                                                            \
    _Pragma("unroll 2") for (int k0 = 0; k0 < 256; k0 += 32) {                 \
        int kk = k0 + lh * 8;                                                  \
        bf16x8 a[4], b[4];                                                     \
        _Pragma("unroll") for (int mt = 0; mt < 4; mt++) {                     \
            int ra = mt * 16 + lr;                                             \
            int blk = ((k0 >> 3) + lh) ^ ((ra & 7) << 2);                      \
            a[mt] = *(const bf16x8*)&A_lds[ra * D + blk * 8];                  \
        }                                                                      \
        _Pragma("unroll") for (int nt = 0; nt < 4; nt++)                       \
            b[nt] = *(const bf16x8*)(wb + (size_t)nt * 16 * KDIM + (koff) + kk);\
        _Pragma("unroll") for (int mt = 0; mt < 4; mt++)                       \
            _Pragma("unroll") for (int nt = 0; nt < 4; nt++)                   \
                acc[mt][nt] = __builtin_amdgcn_mfma_f32_16x16x32_bf16(         \
                    a[mt], b[nt], acc[mt][nt], 0, 0, 0);                       \
    }

    KHALF(0)

    // ---- phase 3: refill A_lds with pre-swizzled bf16(x) rows ----
    __syncthreads();  // all waves done reading half-1 panel
    {
        // wave w refills rows [w*16, w*16+16) = 8KB, as 8 x 1KB linear copies
        const char* src = (const char*)(Xb + (size_t)row0 * D) + wid * 8192;
        char* dst = (char*)A_lds + wid * 8192;
#pragma unroll
        for (int o = 0; o < 8; ++o)
            async_cp16(src + o * 1024 + lane * 16, dst + o * 1024 + lane * 16);
    }
    __syncthreads();  // compiler drains vmcnt before barrier

    // ---- phase 4: GEMM, K half 2 (bf16(x) x W_r) ----
    KHALF(256)
#undef KHALF

    // ---- phase 5: bias + exact GELU + LayerNorm + residual(from A_lds) ----
    float bl[4], ga[4], be[4];
#pragma unroll
    for (int nt = 0; nt < 4; nt++) {
        int c = wid * 64 + nt * 16 + lr;
        bl[nt] = b_l[c];
        ga[nt] = gamma[c];
        be[nt] = beta[c];
    }

#pragma unroll
    for (int mt = 0; mt < 4; mt++) {
#pragma unroll
        for (int r = 0; r < 4; r++) {
            float s = 0.f, q = 0.f;
#pragma unroll
            for (int nt = 0; nt < 4; nt++) {
                float u = acc[mt][nt][r] + bl[nt];
                float ge = 0.5f * u * (1.0f + erff(u * 0.70710678118654752f));
                acc[mt][nt][r] = ge;
                s += ge;
                q += ge * ge;
            }
#pragma unroll
            for (int off = 8; off >= 1; off >>= 1) {
                s += __shfl_xor(s, off, 64);
                q += __shfl_xor(q, off, 64);
            }
            if (lr == 0) {
                int rl = mt * 16 + lh * 4 + r;
                sm_s[wid][rl] = s;
                sm_q[wid][rl] = q;
            }
        }
    }
    __syncthreads();

#pragma unroll
    for (int mt = 0; mt < 4; mt++) {
#pragma unroll
        for (int r = 0; r < 4; r++) {
            int rl = mt * 16 + lh * 4 + r;
            int m = row0 + rl;
            float S = sm_s[0][rl] + sm_s[1][rl] + sm_s[2][rl] + sm_s[3][rl];
            float Q = sm_q[0][rl] + sm_q[1][rl] + sm_q[2][rl] + sm_q[3][rl];
            float mean = S * (1.0f / 256.0f);
            float var = Q * (1.0f / 256.0f) - mean * mean;
            float rstd = rsqrtf(var + 1e-5f);
            if (m < M) {
                int f = (rl & 7) << 2;
#pragma unroll
                for (int nt = 0; nt < 4; nt++) {
                    int c = wid * 64 + nt * 16 + lr;
                    float res = (float)A_lds[rl * D + (((c >> 3) ^ f) << 3) +
                                             (c & 7)];
                    out[(size_t)m * D + c] =
                        (acc[mt][nt][r] - mean) * rstd * ga[nt] + be[nt] + res;
                }
            }
        }
    }
}

// ---------------- launch ----------------

extern "C" void kernel_launch(void* const* d_in, const int* in_sizes, int n_in,
                              void* d_out, int out_size, void* d_ws, size_t ws_size,
                              hipStream_t stream) {
    const float* x = (const float*)d_in[0];
    const int* eidx = (const int*)d_in[1];
    const float* W_l = (const float*)d_in[2];
    const float* b_l = (const float*)d_in[3];
    const float* W_r = (const float*)d_in[4];
    const float* gamma = (const float*)d_in[5];
    const float* beta = (const float*)d_in[6];
    float* out = (float*)d_out;

    const int N = in_sizes[0] / D;
    const int E = in_sizes[1] / 2;
    const int B1 = (N + 255) >> 8;  // 256-node buckets

    char* basep = (char*)d_ws;
    size_t off = 0;
    auto take = [&](size_t bytes) -> void* {
        void* r = basep + off;
        off += (bytes + 255) & ~(size_t)255;
        return r;
    };
    bf16_t* Xb = (bf16_t*)take((size_t)N * D * sizeof(bf16_t));        // 51.2 MB
    unsigned int* Xq = (unsigned int*)take((size_t)N * (D / 4) * 4);   // 25.6 MB
    int* edge_src = (int*)take((size_t)E * sizeof(int));               // 12.8 MB
    bf16_t* Wcat = (bf16_t*)take((size_t)D * KDIM * sizeof(bf16_t));
    int* row_ptr = (int*)take((size_t)(N + 1) * sizeof(int));
    int* bcur = (int*)take((size_t)B1 * 16 * sizeof(int));
    int* bbase = (int*)take((size_t)B1 * sizeof(int));
    // staging (B1*BCAP ints = 25.6MB) aliases Xb (51.2MB): consumed by
    // k_bucket strictly BEFORE k_convx writes Xb.
    int* staging = (int*)Xb;

    hipMemsetAsync(bcur, 0, (size_t)B1 * 16 * sizeof(int), stream);

    k_scatter1<<<(E + EPB - 1) / EPB, 256, 0, stream>>>(eidx, bcur, staging, E);
    k_bbase<<<1, 512, 0, stream>>>(bcur, bbase, row_ptr, B1, N, E);
    k_bucket<<<B1, 256, 0, stream>>>(bcur, bbase, staging, edge_src, row_ptr, N);

    k_convx<<<(N * (D / 8) + 255) / 256, 256, 0, stream>>>(x, Xq, Xb, N * (D / 8));
    k_convw<<<(D * KDIM / 4 + 255) / 256, 256, 0, stream>>>(W_l, W_r, Wcat);

    k_fused<<<(N + BM - 1) / BM, 256, 0, stream>>>(row_ptr, edge_src, Xq, Xb,
                                                   Wcat, b_l, gamma, beta, out, N);
}